// Round 2
// baseline (2936.579 us; speedup 1.0000x reference)
//
#include <hip/hip_runtime.h>
#include <hip/hip_bf16.h>
#include <math.h>

#define NPTS 4096
#define NB 4
#define KNN 20
#define NCOLS (3*NPTS)   // 12288
#define NEG_INF (-__builtin_huge_valf())
#define DNEG_INF (-__builtin_huge_val())

// ---------------------------------------------------------------------------
// kNN in FP64 (exact ordering vs fp64 np reference; inputs are raw fp32 pts).
// One wave per row, 4 rows per 256-thread block.
// tie semantics match jax.lax.top_k: value desc, index asc
// ---------------------------------------------------------------------------
__global__ __launch_bounds__(256) void knn_kernel(const float* __restrict__ pc,
                                                  int* __restrict__ idx) {
  __shared__ float pts[NPTS*3];
  int b = blockIdx.x >> 10;          // 1024 blocks per batch
  int rowblk = blockIdx.x & 1023;
  const float* pb = pc + (size_t)b*NPTS*3;
  for (int i = threadIdx.x; i < NPTS*3; i += 256) pts[i] = pb[i];
  __syncthreads();
  int wave = threadIdx.x >> 6;
  int lane = threadIdx.x & 63;
  int n = rowblk*4 + wave;
  double pn0 = pts[n*3+0], pn1 = pts[n*3+1], pn2 = pts[n*3+2];
  double sqn = pn0*pn0 + pn1*pn1 + pn2*pn2;
  double nd[64];
#pragma unroll
  for (int j = 0; j < 64; ++j) {
    int m = j*64 + lane;            // lane-consecutive -> conflict-free LDS
    double q0 = pts[m*3+0], q1 = pts[m*3+1], q2 = pts[m*3+2];
    double inner = pn0*q0 + pn1*q1 + pn2*q2;
    double sqm = q0*q0 + q1*q1 + q2*q2;
    nd[j] = 2.0*inner - sqn - sqm;
  }
  int* orow = idx + ((size_t)b*NPTS + n)*KNN;
  for (int t = 0; t < KNN; ++t) {
    double bv = nd[0]; int bm = lane;
#pragma unroll
    for (int j = 1; j < 64; ++j) {
      int m = j*64 + lane;
      bool take = nd[j] > bv;       // strict > : ascending m -> first max
      bv = take ? nd[j] : bv;
      bm = take ? m : bm;
    }
#pragma unroll
    for (int s = 1; s < 64; s <<= 1) {
      double ov = __shfl_xor(bv, s, 64);
      int om = __shfl_xor(bm, s, 64);
      bool take = (ov > bv) || (ov == bv && om < bm);
      bv = take ? ov : bv;
      bm = take ? om : bm;
    }
    if (lane == 0) orow[t] = bm;
#pragma unroll
    for (int j = 0; j < 64; ++j) {  // remove winner (compile-time reg indices)
      if (j*64 + lane == bm) nd[j] = DNEG_INF;
    }
  }
}

// ---------------------------------------------------------------------------
// Edge conv in FP64 decisions: feat -> Wf/Wd -> vn_leaky (fp64) -> pool over k
// with pool_pos_Wd dot accumulated in fp64. One wave per point, 4 points per
// 256-thread block. Feature exchange via double shuffles (no LDS). Stored
// activations fp32. Output conv[b][c][v][n].
// ---------------------------------------------------------------------------
__global__ __launch_bounds__(256) void edgeconv_kernel(
    const float* __restrict__ pc, const int* __restrict__ knnidx,
    const float* __restrict__ Wf, const float* __restrict__ Wd,
    const float* __restrict__ Wp, float* __restrict__ outp) {
  __shared__ float xls[4*3840];   // per wave: x[(v*20+kk)*64 + c]
  int wave = threadIdx.x >> 6, lane = threadIdx.x & 63;
  int pid0 = blockIdx.x * 4;
  int b = pid0 >> 12;
  int n0 = pid0 & (NPTS-1);
  int n = n0 + wave;
  const float* pb = pc + (size_t)b*NPTS*3;
  int c = lane;
  float wrow[64];
#pragma unroll
  for (int j = 0; j < 64; ++j) wrow[j] = Wp[c*64 + j];   // row c of Wp
  double wf0 = Wf[c*3+0], wf1 = Wf[c*3+1], wf2 = Wf[c*3+2];
  double wd0 = Wd[c*3+0], wd1 = Wd[c*3+1], wd2 = Wd[c*3+2];
  // features for this wave's point; lane kk holds neighbor kk's 9 values
  double f9[9];
#pragma unroll
  for (int i = 0; i < 9; ++i) f9[i] = 0.0;
  if (lane < KNN) {
    int j = knnidx[((size_t)b*NPTS + n)*KNN + lane];
    double q0 = pb[j*3+0], q1 = pb[j*3+1], q2 = pb[j*3+2];
    double x0 = pb[n*3+0], x1 = pb[n*3+1], x2 = pb[n*3+2];
    f9[0] = q0-x0; f9[1] = q1-x1; f9[2] = q2-x2;          // ch0 = nbr-x
    f9[3] = x0;    f9[4] = x1;    f9[5] = x2;             // ch1 = x
    f9[6] = q1*x2 - q2*x1;                                 // ch2 = cross(nbr,x)
    f9[7] = q2*x0 - q0*x2;
    f9[8] = q0*x1 - q1*x0;
  }
  float* xw = &xls[wave*3840];
  for (int kk = 0; kk < KNN; ++kk) {
    double fch[9];
#pragma unroll
    for (int i = 0; i < 9; ++i) fch[i] = __shfl(f9[i], kk, 64);
    double fv[3], dv[3];
#pragma unroll
    for (int v = 0; v < 3; ++v) {
      fv[v] = wf0*fch[v] + wf1*fch[3+v] + wf2*fch[6+v];
      dv[v] = wd0*fch[v] + wd1*fch[3+v] + wd2*fch[6+v];
    }
    double dot = fv[0]*dv[0] + fv[1]*dv[1] + fv[2]*dv[2];
    if (dot < 0.0) {
      double dsq = dv[0]*dv[0] + dv[1]*dv[1] + dv[2]*dv[2];
      double s = dot / (dsq + 1e-6);
      fv[0] -= s*dv[0]; fv[1] -= s*dv[1]; fv[2] -= s*dv[2];
    }
    xw[(0*20+kk)*64 + c] = (float)fv[0];
    xw[(1*20+kk)*64 + c] = (float)fv[1];
    xw[(2*20+kk)*64 + c] = (float)fv[2];
  }
  __syncthreads();
  // pool over k: d2 = Wp @ x (fp64 accumulate) ; dot over v ; first-max kk
  double bdot = DNEG_INF; int bk = 0;
  for (int kk = 0; kk < KNN; ++kk) {
    double a0 = 0.0, a1 = 0.0, a2 = 0.0;
#pragma unroll
    for (int j = 0; j < 64; j += 4) {
      float4 v0 = *(const float4*)&xw[(0*20+kk)*64 + j];
      float4 v1 = *(const float4*)&xw[(1*20+kk)*64 + j];
      float4 v2 = *(const float4*)&xw[(2*20+kk)*64 + j];
      a0 += (double)wrow[j]*v0.x + (double)wrow[j+1]*v0.y
          + (double)wrow[j+2]*v0.z + (double)wrow[j+3]*v0.w;
      a1 += (double)wrow[j]*v1.x + (double)wrow[j+1]*v1.y
          + (double)wrow[j+2]*v1.z + (double)wrow[j+3]*v1.w;
      a2 += (double)wrow[j]*v2.x + (double)wrow[j+1]*v2.y
          + (double)wrow[j+2]*v2.z + (double)wrow[j+3]*v2.w;
    }
    double xc0 = xw[(0*20+kk)*64 + c];
    double xc1 = xw[(1*20+kk)*64 + c];
    double xc2 = xw[(2*20+kk)*64 + c];
    double dd = xc0*a0 + xc1*a1 + xc2*a2;
    if (dd > bdot) { bdot = dd; bk = kk; }
  }
  float s0 = xw[(0*20+bk)*64 + c];
  float s1 = xw[(1*20+bk)*64 + c];
  float s2 = xw[(2*20+bk)*64 + c];
  __syncthreads();                  // all waves done reading xls
  xls[(c*3+0)*4 + wave] = s0;       // stage for coalesced float4 writes
  xls[(c*3+1)*4 + wave] = s1;
  xls[(c*3+2)*4 + wave] = s2;
  __syncthreads();
  if (threadIdx.x < 192) {
    int cc = threadIdx.x / 3, v = threadIdx.x % 3;
    float4 r = *(const float4*)&xls[(cc*3+v)*4];
    *(float4*)&outp[(((size_t)b*64 + cc)*3 + v)*NPTS + n0] = r;
  }
}

// ---------------------------------------------------------------------------
// Generic vn_lin GEMM: Y[b,row,col] = sum_k W[row,k] X[b,k,col] (+ Z)
// 64x64 tile, 256 threads, 4x4 per thread, K-chunks of 32 in LDS.
// ---------------------------------------------------------------------------
__global__ __launch_bounds__(256) void gemm_vn(
    const float* __restrict__ W, const float* __restrict__ X,
    const float* __restrict__ Z, float* __restrict__ Y,
    int Cout, int Cin, int ncols, long bsX, long bsY, long bsZ, int addZ) {
  __shared__ __align__(16) float Wl[32*68];
  __shared__ __align__(16) float Xl[32*68];
  int b = blockIdx.z;
  int row0 = blockIdx.y * 64, col0 = blockIdx.x * 64;
  const float* Xb = X + (long)b*bsX;
  float acc[4][4] = {};
  int tid = threadIdx.x;
  int rid = tid >> 4, cid = tid & 15;
  for (int k0 = 0; k0 < Cin; k0 += 32) {
    {
      int k = tid & 31, r0 = tid >> 5;
#pragma unroll
      for (int p = 0; p < 8; ++p) {
        int r = r0 + p*8;
        Wl[k*68 + r] = W[(long)(row0 + r)*Cin + k0 + k];
      }
      int cc = tid & 63, kx0 = tid >> 6;
#pragma unroll
      for (int p = 0; p < 8; ++p) {
        int k2 = kx0 + p*4;
        Xl[k2*68 + cc] = Xb[(long)(k0 + k2)*ncols + col0 + cc];
      }
    }
    __syncthreads();
#pragma unroll
    for (int k = 0; k < 32; ++k) {
      float4 w4 = *(const float4*)&Wl[k*68 + rid*4];
      float4 x4 = *(const float4*)&Xl[k*68 + cid*4];
      float w[4] = {w4.x, w4.y, w4.z, w4.w};
      float xv[4] = {x4.x, x4.y, x4.z, x4.w};
#pragma unroll
      for (int i2 = 0; i2 < 4; ++i2)
#pragma unroll
        for (int j2 = 0; j2 < 4; ++j2)
          acc[i2][j2] += w[i2]*xv[j2];
    }
    __syncthreads();
  }
#pragma unroll
  for (int i2 = 0; i2 < 4; ++i2) {
    long base = (long)b*bsY + (long)(row0 + rid*4 + i2)*ncols + col0 + cid*4;
    float4 r = make_float4(acc[i2][0], acc[i2][1], acc[i2][2], acc[i2][3]);
    if (addZ) {
      float4 z = *(const float4*)&Z[(long)b*bsZ + (long)(row0 + rid*4 + i2)*ncols + col0 + cid*4];
      r.x += z.x; r.y += z.y; r.z += z.z; r.w += z.w;
    }
    *(float4*)&Y[base] = r;
  }
}

// ---------------------------------------------------------------------------
// vn_leaky: u = (dot>=0) ? x : x - (dot/(dsq+eps))*d ; writes u over D in-place
// ---------------------------------------------------------------------------
__global__ __launch_bounds__(256) void leaky_kernel(
    const float* __restrict__ X, float* __restrict__ D,
    int C, long bsX, long bsD) {
  long id = (long)blockIdx.x*256 + threadIdx.x;   // B*C*N threads
  int n = (int)(id & (NPTS-1));
  long t = id >> 12;
  int c = (int)(t % C);
  int b = (int)(t / C);
  long xo = (long)b*bsX + (long)c*3*NPTS + n;
  long dxo = (long)b*bsD + (long)c*3*NPTS + n;
  float x0 = X[xo], x1 = X[xo+NPTS], x2 = X[xo+2*NPTS];
  float d0 = D[dxo], d1 = D[dxo+NPTS], d2 = D[dxo+2*NPTS];
  float dot = x0*d0 + x1*d1 + x2*d2;
  float u0 = x0, u1 = x1, u2 = x2;
  if (dot < 0.0f) {
    float dsq = d0*d0 + d1*d1 + d2*d2;
    float s = dot / (dsq + 1e-6f);
    u0 = x0 - s*d0; u1 = x1 - s*d1; u2 = x2 - s*d2;
  }
  D[dxo] = u0; D[dxo+NPTS] = u1; D[dxo+2*NPTS] = u2;
}

// ---------------------------------------------------------------------------
// pool over N: per (b,c) argmax_n sum_v net*d (first max), emit net[:, n*]
// ---------------------------------------------------------------------------
__global__ __launch_bounds__(256) void pool_kernel(
    const float* __restrict__ Net, const float* __restrict__ Dm,
    float* __restrict__ pooled, long bsN, long bsD) {
  __shared__ float sv[256];
  __shared__ int sn[256];
  int c = blockIdx.x, b = blockIdx.y;
  long nb = (long)b*bsN + (long)c*3*NPTS;
  long db = (long)b*bsD + (long)c*3*NPTS;
  float bv = NEG_INF; int bn = 0x7fffffff;
  for (int n = threadIdx.x; n < NPTS; n += 256) {
    float dot = Net[nb+n]*Dm[db+n] + Net[nb+NPTS+n]*Dm[db+NPTS+n]
              + Net[nb+2*NPTS+n]*Dm[db+2*NPTS+n];
    if (dot > bv) { bv = dot; bn = n; }
  }
  sv[threadIdx.x] = bv; sn[threadIdx.x] = bn;
  __syncthreads();
  for (int s = 128; s > 0; s >>= 1) {
    if (threadIdx.x < s) {
      bool take = (sv[threadIdx.x+s] > sv[threadIdx.x]) ||
                  (sv[threadIdx.x+s] == sv[threadIdx.x] && sn[threadIdx.x+s] < sn[threadIdx.x]);
      if (take) { sv[threadIdx.x] = sv[threadIdx.x+s]; sn[threadIdx.x] = sn[threadIdx.x+s]; }
    }
    __syncthreads();
  }
  if (threadIdx.x < 3)
    pooled[((long)b*128 + c)*3 + threadIdx.x] = Net[nb + (long)threadIdx.x*NPTS + sn[0]];
}

// broadcast pooled into channels 128..255 of the concat buffer
__global__ __launch_bounds__(256) void bcast_kernel(
    const float* __restrict__ pooled, float* __restrict__ Xn) {
  long id = (long)blockIdx.x*256 + threadIdx.x;   // B*128*3*N
  int n = (int)(id & (NPTS-1));
  long t = id >> 12;          // b*384 + c*3 + v
  int v = (int)(t % 3); long t2 = t/3;
  int c = (int)(t2 % 128); int b = (int)(t2/128);
  Xn[(long)b*(256*3*NPTS) + (long)(128+c)*3*NPTS + (long)v*NPTS + n] = pooled[t];
}

// ---------------------------------------------------------------------------
// head: c = fcc_W @ vn_leaky(pooled, actc_Wd @ pooled) ; out [B,192]
// ---------------------------------------------------------------------------
__global__ __launch_bounds__(128) void head_kernel(
    const float* __restrict__ pooled, const float* __restrict__ Wa,
    const float* __restrict__ Wc, float* __restrict__ out) {
  __shared__ float xp[128*3], up[128*3];
  int b = blockIdx.x, c = threadIdx.x;
#pragma unroll
  for (int v = 0; v < 3; ++v) xp[c*3+v] = pooled[(long)b*384 + c*3 + v];
  __syncthreads();
  float a0 = 0.f, a1 = 0.f, a2 = 0.f;
  for (int j = 0; j < 128; ++j) {
    float w = Wa[c*128+j];
    a0 += w*xp[j*3+0]; a1 += w*xp[j*3+1]; a2 += w*xp[j*3+2];
  }
  float x0 = xp[c*3+0], x1 = xp[c*3+1], x2 = xp[c*3+2];
  float dot = x0*a0 + x1*a1 + x2*a2;
  float u0 = x0, u1 = x1, u2 = x2;
  if (dot < 0.0f) {
    float dsq = a0*a0 + a1*a1 + a2*a2;
    float s = dot / (dsq + 1e-6f);
    u0 = x0 - s*a0; u1 = x1 - s*a1; u2 = x2 - s*a2;
  }
  up[c*3+0] = u0; up[c*3+1] = u1; up[c*3+2] = u2;
  __syncthreads();
  if (c < 64) {
    float o0 = 0.f, o1 = 0.f, o2 = 0.f;
    for (int j = 0; j < 128; ++j) {
      float w = Wc[c*128+j];
      o0 += w*up[j*3+0]; o1 += w*up[j*3+1]; o2 += w*up[j*3+2];
    }
    out[(long)b*192 + c*3 + 0] = o0;
    out[(long)b*192 + c*3 + 1] = o1;
    out[(long)b*192 + c*3 + 2] = o2;
  }
}

// ---------------------------------------------------------------------------
extern "C" void kernel_launch(void* const* d_in, const int* in_sizes, int n_in,
                              void* d_out, int out_size, void* d_ws, size_t ws_size,
                              hipStream_t stream) {
  const float* pc    = (const float*)d_in[0];
  const float* cWf   = (const float*)d_in[1];
  const float* cWd   = (const float*)d_in[2];
  const float* pposW = (const float*)d_in[3];
  const float* fcW   = (const float*)d_in[4];
  const float* ba0   = (const float*)d_in[5];
  const float* bf0   = (const float*)d_in[6];
  const float* ba1   = (const float*)d_in[7];
  const float* bf1   = (const float*)d_in[8];
  const float* bscW  = (const float*)d_in[9];
  const float* pWd   = (const float*)d_in[10];
  const float* aWd   = (const float*)d_in[11];
  const float* fccW  = (const float*)d_in[12];
  float* out = (float*)d_out;
  char* ws = (char*)d_ws;
  const size_t MB = 1u << 20;
  // workspace layout (~179 MB):
  int*   idxb   = (int*)(ws);                 // 1.25 MB
  float* X1     = (float*)(ws + 2*MB);        // 48 MB  [B,256,3,N]
  float* X2     = (float*)(ws + 52*MB);       // 48 MB  [B,256,3,N]
  float* conv   = (float*)(ws + 52*MB);       // 12 MB  [B,64,3,N] (aliases X2; dead before X2 written)
  float* T      = (float*)(ws + 102*MB);      // 48 MB  [B,256,3,N]
  float* T2     = T;                          // 24 MB  [B,128,3,N] (aliases T; T dead by then)
  float* DX     = (float*)(ws + 126*MB);      // 24 MB  [B,128,3,N]
  float* Hn     = (float*)(ws + 152*MB);      // 24 MB  [B,128,3,N]
  float* pooled = (float*)(ws + 178*MB);      // [B,128,3]

  knn_kernel<<<NB*NPTS/4, 256, 0, stream>>>(pc, idxb);
  edgeconv_kernel<<<NB*NPTS/4, 256, 0, stream>>>(pc, idxb, cWf, cWd, pposW, conv);
  gemm_vn<<<dim3(NCOLS/64, 4, NB), 256, 0, stream>>>(fcW, conv, nullptr, X1,
      256, 64, NCOLS, (long)64*NCOLS, (long)256*NCOLS, 0, 0);

  float* Xin = X1; float* Xout = X2;
  for (int i = 0; i < 5; ++i) {
    const float* a0 = ba0 + (size_t)i*256*256;
    const float* f0 = bf0 + (size_t)i*128*256;
    const float* a1 = ba1 + (size_t)i*128*128;
    const float* f1 = bf1 + (size_t)i*128*128;
    const float* sc = bscW + (size_t)i*128*256;
    const float* pw = pWd + (size_t)i*128*128;
    // T = a0 @ X ; U = leaky(X, T) in-place
    gemm_vn<<<dim3(192,4,NB),256,0,stream>>>(a0, Xin, nullptr, T,
        256, 256, NCOLS, (long)256*NCOLS, (long)256*NCOLS, 0, 0);
    leaky_kernel<<<NB*256*NPTS/256,256,0,stream>>>(Xin, T, 256,
        (long)256*NCOLS, (long)256*NCOLS);
    // Hn = f0 @ U
    gemm_vn<<<dim3(192,2,NB),256,0,stream>>>(f0, T, nullptr, Hn,
        128, 256, NCOLS, (long)256*NCOLS, (long)128*NCOLS, 0, 0);
    // T2 = a1 @ Hn ; U2 = leaky(Hn, T2) in-place
    gemm_vn<<<dim3(192,2,NB),256,0,stream>>>(a1, Hn, nullptr, T2,
        128, 128, NCOLS, (long)128*NCOLS, (long)128*NCOLS, 0, 0);
    leaky_kernel<<<NB*128*NPTS/256,256,0,stream>>>(Hn, T2, 128,
        (long)128*NCOLS, (long)128*NCOLS);
    // DX = f1 @ U2
    gemm_vn<<<dim3(192,2,NB),256,0,stream>>>(f1, T2, nullptr, DX,
        128, 128, NCOLS, (long)128*NCOLS, (long)128*NCOLS, 0, 0);
    // Xout[ch 0..127] = sc @ Xin + DX
    gemm_vn<<<dim3(192,2,NB),256,0,stream>>>(sc, Xin, DX, Xout,
        128, 256, NCOLS, (long)256*NCOLS, (long)256*NCOLS, (long)128*NCOLS, 1);
    // D = pw @ net (net = Xout ch 0..127) -> Hn (reused)
    gemm_vn<<<dim3(192,2,NB),256,0,stream>>>(pw, Xout, nullptr, Hn,
        128, 128, NCOLS, (long)256*NCOLS, (long)128*NCOLS, 0, 0);
    pool_kernel<<<dim3(128,NB),256,0,stream>>>(Xout, Hn, pooled,
        (long)256*NCOLS, (long)128*NCOLS);
    if (i < 4) {
      bcast_kernel<<<NB*128*3*NPTS/256,256,0,stream>>>(pooled, Xout);
      float* tmp = Xin; Xin = Xout; Xout = tmp;
    }
  }
  head_kernel<<<NB,128,0,stream>>>(pooled, aWd, fccW, out);
}

// Round 4
// 2218.640 us; speedup vs baseline: 1.3236x; 1.3236x over previous
//
#include <hip/hip_runtime.h>
#include <hip/hip_bf16.h>
#include <math.h>

#define NPTS 4096
#define NB 4
#define KNN 20
#define NCOLS (3*NPTS)   // 12288
#define NEG_INF (-__builtin_huge_valf())
#define DNEG_INF (-__builtin_huge_val())

typedef _Float16 f16x8 __attribute__((ext_vector_type(8)));
typedef float f32x4 __attribute__((ext_vector_type(4)));

// ---------------------------------------------------------------------------
// kNN in FP64 (exact ordering vs fp64 np reference). One wave per row.
// ---------------------------------------------------------------------------
__global__ __launch_bounds__(256) void knn_kernel(const float* __restrict__ pc,
                                                  int* __restrict__ idx) {
  __shared__ float pts[NPTS*3];
  int b = blockIdx.x >> 10;
  int rowblk = blockIdx.x & 1023;
  const float* pb = pc + (size_t)b*NPTS*3;
  for (int i = threadIdx.x; i < NPTS*3; i += 256) pts[i] = pb[i];
  __syncthreads();
  int wave = threadIdx.x >> 6;
  int lane = threadIdx.x & 63;
  int n = rowblk*4 + wave;
  double pn0 = pts[n*3+0], pn1 = pts[n*3+1], pn2 = pts[n*3+2];
  double sqn = pn0*pn0 + pn1*pn1 + pn2*pn2;
  double nd[64];
#pragma unroll
  for (int j = 0; j < 64; ++j) {
    int m = j*64 + lane;
    double q0 = pts[m*3+0], q1 = pts[m*3+1], q2 = pts[m*3+2];
    double inner = pn0*q0 + pn1*q1 + pn2*q2;
    double sqm = q0*q0 + q1*q1 + q2*q2;
    nd[j] = 2.0*inner - sqn - sqm;
  }
  int* orow = idx + ((size_t)b*NPTS + n)*KNN;
  for (int t = 0; t < KNN; ++t) {
    double bv = nd[0]; int bm = lane;
#pragma unroll
    for (int j = 1; j < 64; ++j) {
      int m = j*64 + lane;
      bool take = nd[j] > bv;
      bv = take ? nd[j] : bv;
      bm = take ? m : bm;
    }
#pragma unroll
    for (int s = 1; s < 64; s <<= 1) {
      double ov = __shfl_xor(bv, s, 64);
      int om = __shfl_xor(bm, s, 64);
      bool take = (ov > bv) || (ov == bv && om < bm);
      bv = take ? ov : bv;
      bm = take ? om : bm;
    }
    if (lane == 0) orow[t] = bm;
#pragma unroll
    for (int j = 0; j < 64; ++j) {
      if (j*64 + lane == bm) nd[j] = DNEG_INF;
    }
  }
}

// ---------------------------------------------------------------------------
// Edge conv (fp64 decisions). Output channel-fast: conv[b][v*N+n][c], c<64.
// ---------------------------------------------------------------------------
__global__ __launch_bounds__(256) void edgeconv_kernel(
    const float* __restrict__ pc, const int* __restrict__ knnidx,
    const float* __restrict__ Wf, const float* __restrict__ Wd,
    const float* __restrict__ Wp, float* __restrict__ outp) {
  __shared__ float xls[4*3840];   // per wave: x[(v*20+kk)*64 + c]
  int wave = threadIdx.x >> 6, lane = threadIdx.x & 63;
  int pid0 = blockIdx.x * 4;
  int b = pid0 >> 12;
  int n = (pid0 & (NPTS-1)) + wave;
  const float* pb = pc + (size_t)b*NPTS*3;
  int c = lane;
  float wrow[64];
#pragma unroll
  for (int j = 0; j < 64; ++j) wrow[j] = Wp[c*64 + j];
  double wf0 = Wf[c*3+0], wf1 = Wf[c*3+1], wf2 = Wf[c*3+2];
  double wd0 = Wd[c*3+0], wd1 = Wd[c*3+1], wd2 = Wd[c*3+2];
  double f9[9];
#pragma unroll
  for (int i = 0; i < 9; ++i) f9[i] = 0.0;
  if (lane < KNN) {
    int j = knnidx[((size_t)b*NPTS + n)*KNN + lane];
    double q0 = pb[j*3+0], q1 = pb[j*3+1], q2 = pb[j*3+2];
    double x0 = pb[n*3+0], x1 = pb[n*3+1], x2 = pb[n*3+2];
    f9[0] = q0-x0; f9[1] = q1-x1; f9[2] = q2-x2;
    f9[3] = x0;    f9[4] = x1;    f9[5] = x2;
    f9[6] = q1*x2 - q2*x1;
    f9[7] = q2*x0 - q0*x2;
    f9[8] = q0*x1 - q1*x0;
  }
  float* xw = &xls[wave*3840];
  for (int kk = 0; kk < KNN; ++kk) {
    double fch[9];
#pragma unroll
    for (int i = 0; i < 9; ++i) fch[i] = __shfl(f9[i], kk, 64);
    double fv[3], dv[3];
#pragma unroll
    for (int v = 0; v < 3; ++v) {
      fv[v] = wf0*fch[v] + wf1*fch[3+v] + wf2*fch[6+v];
      dv[v] = wd0*fch[v] + wd1*fch[3+v] + wd2*fch[6+v];
    }
    double dot = fv[0]*dv[0] + fv[1]*dv[1] + fv[2]*dv[2];
    if (dot < 0.0) {
      double dsq = dv[0]*dv[0] + dv[1]*dv[1] + dv[2]*dv[2];
      double s = dot / (dsq + 1e-6);
      fv[0] -= s*dv[0]; fv[1] -= s*dv[1]; fv[2] -= s*dv[2];
    }
    xw[(0*20+kk)*64 + c] = (float)fv[0];
    xw[(1*20+kk)*64 + c] = (float)fv[1];
    xw[(2*20+kk)*64 + c] = (float)fv[2];
  }
  __syncthreads();
  double bdot = DNEG_INF; int bk = 0;
  for (int kk = 0; kk < KNN; ++kk) {
    double a0 = 0.0, a1 = 0.0, a2 = 0.0;
#pragma unroll
    for (int j = 0; j < 64; j += 4) {
      float4 v0 = *(const float4*)&xw[(0*20+kk)*64 + j];
      float4 v1 = *(const float4*)&xw[(1*20+kk)*64 + j];
      float4 v2 = *(const float4*)&xw[(2*20+kk)*64 + j];
      a0 += (double)wrow[j]*v0.x + (double)wrow[j+1]*v0.y
          + (double)wrow[j+2]*v0.z + (double)wrow[j+3]*v0.w;
      a1 += (double)wrow[j]*v1.x + (double)wrow[j+1]*v1.y
          + (double)wrow[j+2]*v1.z + (double)wrow[j+3]*v1.w;
      a2 += (double)wrow[j]*v2.x + (double)wrow[j+1]*v2.y
          + (double)wrow[j+2]*v2.z + (double)wrow[j+3]*v2.w;
    }
    double xc0 = xw[(0*20+kk)*64 + c];
    double xc1 = xw[(1*20+kk)*64 + c];
    double xc2 = xw[(2*20+kk)*64 + c];
    double dd = xc0*a0 + xc1*a1 + xc2*a2;
    if (dd > bdot) { bdot = dd; bk = kk; }
  }
#pragma unroll
  for (int v = 0; v < 3; ++v)
    outp[((size_t)b*NCOLS + v*NPTS + n)*64 + c] = xw[(v*20+bk)*64 + c];
}

// ---------------------------------------------------------------------------
// MFMA GEMM, fp16x2 split (3 products ~ fp32 accuracy).
// Y[b][sp][co] = sum_k X[b][sp][k] * W[co][k]  (channel-fast)
// 128x128 tile, 4 waves, 4x4 16x16x32 fragments each, K_STEP=32.
// ---------------------------------------------------------------------------
#define LDP 40
__global__ __launch_bounds__(256) void gemm_mfma(
    const float* __restrict__ W, const float* __restrict__ X,
    const float* __restrict__ Z, float* __restrict__ Y,
    int Cin, int ldX, int ldY, int ldZ, int addZ) {
  __shared__ __align__(16) _Float16 Ah[128*LDP];
  __shared__ __align__(16) _Float16 Al[128*LDP];
  __shared__ __align__(16) _Float16 Bh[128*LDP];
  __shared__ __align__(16) _Float16 Bl[128*LDP];
  int b = blockIdx.z;
  int sp0 = blockIdx.x * 128;
  int co0 = blockIdx.y * 128;
  const float* Xb = X + ((size_t)b*NCOLS + sp0) * ldX;
  int t = threadIdx.x;
  int srow = t >> 1;
  int skoff = (t & 1) * 16;
  int wid = t >> 6, lane = t & 63;
  int wr = (wid >> 1) * 64, wc = (wid & 1) * 64;
  int lrow = lane & 15, lk = (lane >> 4) * 8;
  f32x4 acc[4][4];
#pragma unroll
  for (int f = 0; f < 4; ++f)
#pragma unroll
    for (int g = 0; g < 4; ++g)
#pragma unroll
      for (int r = 0; r < 4; ++r) acc[f][g][r] = 0.0f;

  for (int k0 = 0; k0 < Cin; k0 += 32) {
    const float* xs = Xb + (size_t)srow*ldX + k0 + skoff;
    const float* wsrc = W + (size_t)(co0 + srow)*Cin + k0 + skoff;
    float xv[16], wv[16];
    *(float4*)&xv[0]  = *(const float4*)&xs[0];
    *(float4*)&xv[4]  = *(const float4*)&xs[4];
    *(float4*)&xv[8]  = *(const float4*)&xs[8];
    *(float4*)&xv[12] = *(const float4*)&xs[12];
    *(float4*)&wv[0]  = *(const float4*)&wsrc[0];
    *(float4*)&wv[4]  = *(const float4*)&wsrc[4];
    *(float4*)&wv[8]  = *(const float4*)&wsrc[8];
    *(float4*)&wv[12] = *(const float4*)&wsrc[12];
    _Float16 xh[16], xl[16], wh[16], wl[16];
#pragma unroll
    for (int j = 0; j < 16; ++j) {
      _Float16 h = (_Float16)xv[j];
      xh[j] = h; xl[j] = (_Float16)(xv[j] - (float)h);
      _Float16 hw = (_Float16)wv[j];
      wh[j] = hw; wl[j] = (_Float16)(wv[j] - (float)hw);
    }
    *(f16x8*)&Ah[srow*LDP + skoff]     = *(f16x8*)&xh[0];
    *(f16x8*)&Ah[srow*LDP + skoff + 8] = *(f16x8*)&xh[8];
    *(f16x8*)&Al[srow*LDP + skoff]     = *(f16x8*)&xl[0];
    *(f16x8*)&Al[srow*LDP + skoff + 8] = *(f16x8*)&xl[8];
    *(f16x8*)&Bh[srow*LDP + skoff]     = *(f16x8*)&wh[0];
    *(f16x8*)&Bh[srow*LDP + skoff + 8] = *(f16x8*)&wh[8];
    *(f16x8*)&Bl[srow*LDP + skoff]     = *(f16x8*)&wl[0];
    *(f16x8*)&Bl[srow*LDP + skoff + 8] = *(f16x8*)&wl[8];
    __syncthreads();
    f16x8 ah[4], al[4], bh[4], bl[4];
#pragma unroll
    for (int f = 0; f < 4; ++f) {
      ah[f] = *(f16x8*)&Ah[(wr + f*16 + lrow)*LDP + lk];
      al[f] = *(f16x8*)&Al[(wr + f*16 + lrow)*LDP + lk];
      bh[f] = *(f16x8*)&Bh[(wc + f*16 + lrow)*LDP + lk];
      bl[f] = *(f16x8*)&Bl[(wc + f*16 + lrow)*LDP + lk];
    }
#pragma unroll
    for (int f = 0; f < 4; ++f)
#pragma unroll
      for (int g = 0; g < 4; ++g) {
        acc[f][g] = __builtin_amdgcn_mfma_f32_16x16x32_f16(ah[f], bh[g], acc[f][g], 0, 0, 0);
        acc[f][g] = __builtin_amdgcn_mfma_f32_16x16x32_f16(ah[f], bl[g], acc[f][g], 0, 0, 0);
        acc[f][g] = __builtin_amdgcn_mfma_f32_16x16x32_f16(al[f], bh[g], acc[f][g], 0, 0, 0);
      }
    __syncthreads();
  }
  int lr0 = (lane >> 4) * 4, lc = lane & 15;
#pragma unroll
  for (int f = 0; f < 4; ++f)
#pragma unroll
    for (int g = 0; g < 4; ++g)
#pragma unroll
      for (int r = 0; r < 4; ++r) {
        int sp = sp0 + wr + f*16 + lr0 + r;
        int co = co0 + wc + g*16 + lc;
        float val = acc[f][g][r];
        if (addZ) val += Z[((size_t)b*NCOLS + sp)*ldZ + co];
        Y[((size_t)b*NCOLS + sp)*ldY + co] = val;
      }
}

// ---------------------------------------------------------------------------
// vn_leaky (channel-fast): D[col][c] updated in place.
// ---------------------------------------------------------------------------
__global__ __launch_bounds__(256) void leaky_kernel(
    const float* __restrict__ X, float* __restrict__ D,
    int cmask, int cshift, int ld) {
  long id = (long)blockIdx.x*256 + threadIdx.x;
  int c = (int)(id & cmask);
  long r = id >> cshift;
  int n = (int)(r & (NPTS-1));
  int b = (int)(r >> 12);
  size_t base = ((size_t)b*NCOLS + n)*ld + c;
  size_t vs = (size_t)NPTS*ld;
  float x0 = X[base], x1 = X[base+vs], x2 = X[base+2*vs];
  float d0 = D[base], d1 = D[base+vs], d2 = D[base+2*vs];
  float dot = x0*d0 + x1*d1 + x2*d2;
  float u0 = x0, u1 = x1, u2 = x2;
  if (dot < 0.0f) {
    float dsq = d0*d0 + d1*d1 + d2*d2;
    float s = dot / (dsq + 1e-6f);
    u0 = x0 - s*d0; u1 = x1 - s*d1; u2 = x2 - s*d2;
  }
  D[base] = u0; D[base+vs] = u1; D[base+2*vs] = u2;
}

// ---------------------------------------------------------------------------
// pool over N — PER-CHANNEL argmax (matches reference: argmax per (b,c)).
// stage 1: block = (b, 256-n chunk); thread = (c, parity). fp64 dot,
// ascending-n strict-> (first max); halves merged with (value, smaller n).
// ---------------------------------------------------------------------------
__global__ __launch_bounds__(256) void pool1_kernel(
    const float* __restrict__ Net, const float* __restrict__ Dm,
    double* __restrict__ pv, int* __restrict__ pn, int ldN, int ldD) {
  __shared__ double sv[256];
  __shared__ int sn[256];
  int b = blockIdx.y;
  int n0 = blockIdx.x * 256;
  int c = threadIdx.x & 127;
  int half = threadIdx.x >> 7;
  double bv = DNEG_INF; int bn = 0x7fffffff;
  for (int i = 0; i < 128; ++i) {
    int n = n0 + 2*i + half;
    size_t r0 = ((size_t)b*NCOLS + n);
    double dot =
        (double)Net[(r0)*ldN + c]              * (double)Dm[(r0)*ldD + c]
      + (double)Net[(r0 + NPTS)*ldN + c]       * (double)Dm[(r0 + NPTS)*ldD + c]
      + (double)Net[(r0 + 2*NPTS)*ldN + c]     * (double)Dm[(r0 + 2*NPTS)*ldD + c];
    if (dot > bv) { bv = dot; bn = n; }
  }
  sv[threadIdx.x] = bv; sn[threadIdx.x] = bn;
  __syncthreads();
  if (half == 0) {
    double v1 = sv[threadIdx.x + 128]; int n1 = sn[threadIdx.x + 128];
    if (v1 > bv || (v1 == bv && n1 < bn)) { bv = v1; bn = n1; }
    pv[((size_t)b*16 + blockIdx.x)*128 + c] = bv;
    pn[((size_t)b*16 + blockIdx.x)*128 + c] = bn;
  }
}

// stage 2: per (b,c) merge 16 chunk partials (ascending n order), gather.
__global__ __launch_bounds__(128) void pool2_kernel(
    const double* __restrict__ pv, const int* __restrict__ pn,
    const float* __restrict__ Net, float* __restrict__ pooled, int ldN) {
  int b = blockIdx.x, c = threadIdx.x;
  double bv = DNEG_INF; int bn = 0x7fffffff;
  for (int ch = 0; ch < 16; ++ch) {
    double v = pv[((size_t)b*16 + ch)*128 + c];
    int nn = pn[((size_t)b*16 + ch)*128 + c];
    if (v > bv || (v == bv && nn < bn)) { bv = v; bn = nn; }
  }
#pragma unroll
  for (int v = 0; v < 3; ++v)
    pooled[(size_t)b*384 + c*3 + v] = Net[((size_t)b*NCOLS + v*NPTS + bn)*ldN + c];
}

// broadcast pooled into channels 128..255 (channel-fast)
__global__ __launch_bounds__(256) void bcast_kernel(
    const float* __restrict__ pooled, float* __restrict__ Xn) {
  int b = blockIdx.y;
  int id = blockIdx.x*256 + threadIdx.x;   // NCOLS*128
  int c = id & 127;
  int col = id >> 7;
  int v = col >> 12;
  Xn[((size_t)b*NCOLS + col)*256 + 128 + c] = pooled[(size_t)b*384 + c*3 + v];
}

// ---------------------------------------------------------------------------
// head: c = fcc_W @ vn_leaky(pooled, actc_Wd @ pooled) ; out [B,192]
// ---------------------------------------------------------------------------
__global__ __launch_bounds__(128) void head_kernel(
    const float* __restrict__ pooled, const float* __restrict__ Wa,
    const float* __restrict__ Wc, float* __restrict__ out) {
  __shared__ float xp[128*3], up[128*3];
  int b = blockIdx.x, c = threadIdx.x;
#pragma unroll
  for (int v = 0; v < 3; ++v) xp[c*3+v] = pooled[(size_t)b*384 + c*3 + v];
  __syncthreads();
  float a0 = 0.f, a1 = 0.f, a2 = 0.f;
  for (int j = 0; j < 128; ++j) {
    float w = Wa[c*128+j];
    a0 += w*xp[j*3+0]; a1 += w*xp[j*3+1]; a2 += w*xp[j*3+2];
  }
  float x0 = xp[c*3+0], x1 = xp[c*3+1], x2 = xp[c*3+2];
  float dot = x0*a0 + x1*a1 + x2*a2;
  float u0 = x0, u1 = x1, u2 = x2;
  if (dot < 0.0f) {
    float dsq = a0*a0 + a1*a1 + a2*a2;
    float s = dot / (dsq + 1e-6f);
    u0 = x0 - s*a0; u1 = x1 - s*a1; u2 = x2 - s*a2;
  }
  up[c*3+0] = u0; up[c*3+1] = u1; up[c*3+2] = u2;
  __syncthreads();
  if (c < 64) {
    float o0 = 0.f, o1 = 0.f, o2 = 0.f;
    for (int j = 0; j < 128; ++j) {
      float w = Wc[c*128+j];
      o0 += w*up[j*3+0]; o1 += w*up[j*3+1]; o2 += w*up[j*3+2];
    }
    out[(size_t)b*192 + c*3 + 0] = o0;
    out[(size_t)b*192 + c*3 + 1] = o1;
    out[(size_t)b*192 + c*3 + 2] = o2;
  }
}

// ---------------------------------------------------------------------------
extern "C" void kernel_launch(void* const* d_in, const int* in_sizes, int n_in,
                              void* d_out, int out_size, void* d_ws, size_t ws_size,
                              hipStream_t stream) {
  const float* pc    = (const float*)d_in[0];
  const float* cWf   = (const float*)d_in[1];
  const float* cWd   = (const float*)d_in[2];
  const float* pposW = (const float*)d_in[3];
  const float* fcW   = (const float*)d_in[4];
  const float* ba0   = (const float*)d_in[5];
  const float* bf0   = (const float*)d_in[6];
  const float* ba1   = (const float*)d_in[7];
  const float* bf1   = (const float*)d_in[8];
  const float* bscW  = (const float*)d_in[9];
  const float* pWd   = (const float*)d_in[10];
  const float* aWd   = (const float*)d_in[11];
  const float* fccW  = (const float*)d_in[12];
  float* out = (float*)d_out;
  char* ws = (char*)d_ws;
  const size_t MB = 1u << 20;
  const size_t KB = 1u << 10;
  // workspace (channel-fast activations [b][col][c]):
  int*    idxb   = (int*)(ws);                 // 1.25 MB
  float*  X1     = (float*)(ws + 2*MB);        // 48 MB  [B][NCOLS][256]
  float*  X2     = (float*)(ws + 52*MB);       // 48 MB
  float*  conv   = (float*)(ws + 52*MB);       // 12 MB [B][NCOLS][64] (aliases X2)
  float*  T      = (float*)(ws + 102*MB);      // 48 MB [B][NCOLS][256]
  float*  T2     = T;                          // 24 MB [B][NCOLS][128] (aliases T)
  float*  DX     = (float*)(ws + 126*MB);      // 24 MB [B][NCOLS][128]
  float*  Hn     = (float*)(ws + 152*MB);      // 24 MB [B][NCOLS][128]
  float*  pooled = (float*)(ws + 178*MB);      // [B][384]
  double* pv     = (double*)(ws + 178*MB + 64*KB);   // 64 KB [B][16][128]
  int*    pn     = (int*)(ws + 178*MB + 128*KB);     // 32 KB

  knn_kernel<<<NB*NPTS/4, 256, 0, stream>>>(pc, idxb);
  edgeconv_kernel<<<NB*NPTS/4, 256, 0, stream>>>(pc, idxb, cWf, cWd, pposW, conv);
  gemm_mfma<<<dim3(96, 2, NB), 256, 0, stream>>>(fcW, conv, nullptr, X1,
      64, 64, 256, 0, 0);

  float* Xin = X1; float* Xout = X2;
  for (int i = 0; i < 5; ++i) {
    const float* a0 = ba0 + (size_t)i*256*256;
    const float* f0 = bf0 + (size_t)i*128*256;
    const float* a1 = ba1 + (size_t)i*128*128;
    const float* f1 = bf1 + (size_t)i*128*128;
    const float* sc = bscW + (size_t)i*128*256;
    const float* pw = pWd + (size_t)i*128*128;
    // T = a0 @ X ; U = leaky(X, T) in place
    gemm_mfma<<<dim3(96,2,NB),256,0,stream>>>(a0, Xin, nullptr, T, 256, 256, 256, 0, 0);
    leaky_kernel<<<NB*NPTS*256/256,256,0,stream>>>(Xin, T, 255, 8, 256);
    // Hn = f0 @ U
    gemm_mfma<<<dim3(96,1,NB),256,0,stream>>>(f0, T, nullptr, Hn, 256, 256, 128, 0, 0);
    // T2 = a1 @ Hn ; U2 = leaky(Hn, T2)
    gemm_mfma<<<dim3(96,1,NB),256,0,stream>>>(a1, Hn, nullptr, T2, 128, 128, 128, 0, 0);
    leaky_kernel<<<NB*NPTS*128/256,256,0,stream>>>(Hn, T2, 127, 7, 128);
    // DX = f1 @ U2
    gemm_mfma<<<dim3(96,1,NB),256,0,stream>>>(f1, T2, nullptr, DX, 128, 128, 128, 0, 0);
    // Xout[ch 0..127] = sc @ Xin + DX
    gemm_mfma<<<dim3(96,1,NB),256,0,stream>>>(sc, Xin, DX, Xout, 256, 256, 256, 128, 1);
    // Dm = pw @ net -> Hn
    gemm_mfma<<<dim3(96,1,NB),256,0,stream>>>(pw, Xout, nullptr, Hn, 128, 256, 128, 0, 0);
    pool1_kernel<<<dim3(16,NB),256,0,stream>>>(Xout, Hn, pv, pn, 256, 128);
    pool2_kernel<<<NB,128,0,stream>>>(pv, pn, Xout, pooled, 256);
    if (i < 4) {
      bcast_kernel<<<dim3(NCOLS*128/256,NB),256,0,stream>>>(pooled, Xout);
      float* tmp = Xin; Xin = Xout; Xout = tmp;
    }
  }
  head_kernel<<<NB,128,0,stream>>>(pooled, aWd, fccW, out);
}

// Round 5
// 1816.268 us; speedup vs baseline: 1.6168x; 1.2215x over previous
//
#include <hip/hip_runtime.h>
#include <hip/hip_bf16.h>
#include <math.h>

#define NPTS 4096
#define NB 4
#define KNN 20
#define NCOLS (3*NPTS)   // 12288
#define NEG_INF (-__builtin_huge_valf())
#define DNEG_INF (-__builtin_huge_val())

typedef _Float16 f16x8 __attribute__((ext_vector_type(8)));
typedef float f32x4 __attribute__((ext_vector_type(4)));

// ---------------------------------------------------------------------------
// kNN in FP64 (exact ordering vs fp64 np reference). One wave per row.
// ---------------------------------------------------------------------------
__global__ __launch_bounds__(256) void knn_kernel(const float* __restrict__ pc,
                                                  int* __restrict__ idx) {
  __shared__ float pts[NPTS*3];
  int b = blockIdx.x >> 10;
  int rowblk = blockIdx.x & 1023;
  const float* pb = pc + (size_t)b*NPTS*3;
  for (int i = threadIdx.x; i < NPTS*3; i += 256) pts[i] = pb[i];
  __syncthreads();
  int wave = threadIdx.x >> 6;
  int lane = threadIdx.x & 63;
  int n = rowblk*4 + wave;
  double pn0 = pts[n*3+0], pn1 = pts[n*3+1], pn2 = pts[n*3+2];
  double sqn = pn0*pn0 + pn1*pn1 + pn2*pn2;
  double nd[64];
#pragma unroll
  for (int j = 0; j < 64; ++j) {
    int m = j*64 + lane;
    double q0 = pts[m*3+0], q1 = pts[m*3+1], q2 = pts[m*3+2];
    double inner = pn0*q0 + pn1*q1 + pn2*q2;
    double sqm = q0*q0 + q1*q1 + q2*q2;
    nd[j] = 2.0*inner - sqn - sqm;
  }
  int* orow = idx + ((size_t)b*NPTS + n)*KNN;
  for (int t = 0; t < KNN; ++t) {
    double bv = nd[0]; int bm = lane;
#pragma unroll
    for (int j = 1; j < 64; ++j) {
      int m = j*64 + lane;
      bool take = nd[j] > bv;
      bv = take ? nd[j] : bv;
      bm = take ? m : bm;
    }
#pragma unroll
    for (int s = 1; s < 64; s <<= 1) {
      double ov = __shfl_xor(bv, s, 64);
      int om = __shfl_xor(bm, s, 64);
      bool take = (ov > bv) || (ov == bv && om < bm);
      bv = take ? ov : bv;
      bm = take ? om : bm;
    }
    if (lane == 0) orow[t] = bm;
#pragma unroll
    for (int j = 0; j < 64; ++j) {
      if (j*64 + lane == bm) nd[j] = DNEG_INF;
    }
  }
}

// ---------------------------------------------------------------------------
// Edge conv v2 — all fp32 (leaky branch is continuous; argmax inputs are
// already fp32-quantized), fp64 only for the final 3-term dot + compare.
// 2 waves (2 points) per 128-thread block; xw is wave-private (no barriers).
// Output channel-fast: conv[b][v*N+n][c], c<64.
// ---------------------------------------------------------------------------
__global__ __launch_bounds__(128) void edgeconv_kernel(
    const float* __restrict__ pc, const int* __restrict__ knnidx,
    const float* __restrict__ Wf, const float* __restrict__ Wd,
    const float* __restrict__ Wp, float* __restrict__ outp) {
  __shared__ float xls[2*3840];   // per wave: x[(v*20+kk)*64 + c]
  int wave = threadIdx.x >> 6, lane = threadIdx.x & 63;
  int pid0 = blockIdx.x * 2;
  int b = pid0 >> 12;
  int n = (pid0 & (NPTS-1)) + wave;
  const float* pb = pc + (size_t)b*NPTS*3;
  int c = lane;
  float wrow[64];
#pragma unroll
  for (int j = 0; j < 64; ++j) wrow[j] = Wp[c*64 + j];
  float wf0 = Wf[c*3+0], wf1 = Wf[c*3+1], wf2 = Wf[c*3+2];
  float wd0 = Wd[c*3+0], wd1 = Wd[c*3+1], wd2 = Wd[c*3+2];
  float f9[9];
#pragma unroll
  for (int i = 0; i < 9; ++i) f9[i] = 0.0f;
  if (lane < KNN) {
    int j = knnidx[((size_t)b*NPTS + n)*KNN + lane];
    float q0 = pb[j*3+0], q1 = pb[j*3+1], q2 = pb[j*3+2];
    float x0 = pb[n*3+0], x1 = pb[n*3+1], x2 = pb[n*3+2];
    f9[0] = q0-x0; f9[1] = q1-x1; f9[2] = q2-x2;
    f9[3] = x0;    f9[4] = x1;    f9[5] = x2;
    f9[6] = q1*x2 - q2*x1;
    f9[7] = q2*x0 - q0*x2;
    f9[8] = q0*x1 - q1*x0;
  }
  float* xw = &xls[wave*3840];
  for (int kk = 0; kk < KNN; ++kk) {
    float fch[9];
#pragma unroll
    for (int i = 0; i < 9; ++i) fch[i] = __shfl(f9[i], kk, 64);
    float fv[3], dv[3];
#pragma unroll
    for (int v = 0; v < 3; ++v) {
      fv[v] = wf0*fch[v] + wf1*fch[3+v] + wf2*fch[6+v];
      dv[v] = wd0*fch[v] + wd1*fch[3+v] + wd2*fch[6+v];
    }
    float dot = fv[0]*dv[0] + fv[1]*dv[1] + fv[2]*dv[2];
    if (dot < 0.0f) {
      float dsq = dv[0]*dv[0] + dv[1]*dv[1] + dv[2]*dv[2];
      float s = dot / (dsq + 1e-6f);
      fv[0] -= s*dv[0]; fv[1] -= s*dv[1]; fv[2] -= s*dv[2];
    }
    xw[(0*20+kk)*64 + c] = fv[0];
    xw[(1*20+kk)*64 + c] = fv[1];
    xw[(2*20+kk)*64 + c] = fv[2];
  }
  // pool over k (per channel c): matvec fp32, final dot+compare fp64
  double bdot = DNEG_INF; int bk = 0;
  for (int kk = 0; kk < KNN; ++kk) {
    float a0 = 0.f, a1 = 0.f, a2 = 0.f;
#pragma unroll
    for (int j = 0; j < 64; j += 4) {
      float4 v0 = *(const float4*)&xw[(0*20+kk)*64 + j];
      float4 v1 = *(const float4*)&xw[(1*20+kk)*64 + j];
      float4 v2 = *(const float4*)&xw[(2*20+kk)*64 + j];
      a0 += wrow[j]*v0.x + wrow[j+1]*v0.y + wrow[j+2]*v0.z + wrow[j+3]*v0.w;
      a1 += wrow[j]*v1.x + wrow[j+1]*v1.y + wrow[j+2]*v1.z + wrow[j+3]*v1.w;
      a2 += wrow[j]*v2.x + wrow[j+1]*v2.y + wrow[j+2]*v2.z + wrow[j+3]*v2.w;
    }
    double dd = (double)xw[(0*20+kk)*64 + c]*a0
              + (double)xw[(1*20+kk)*64 + c]*a1
              + (double)xw[(2*20+kk)*64 + c]*a2;
    if (dd > bdot) { bdot = dd; bk = kk; }
  }
#pragma unroll
  for (int v = 0; v < 3; ++v)
    outp[((size_t)b*NCOLS + v*NPTS + n)*64 + c] = xw[(v*20+bk)*64 + c];
}

// ---------------------------------------------------------------------------
// MFMA GEMM, fp16x2 split (3 products ~ fp32 accuracy).
// Y[b][sp][co] = sum_k X[b][sp][k] * W[co][k]  (channel-fast)
// 128x128 tile, 4 waves, 4x4 16x16x32 fragments each, K_STEP=32.
// ---------------------------------------------------------------------------
#define LDP 40
__global__ __launch_bounds__(256) void gemm_mfma(
    const float* __restrict__ W, const float* __restrict__ X,
    const float* __restrict__ Z, float* __restrict__ Y,
    int Cin, int ldX, int ldY, int ldZ, int addZ) {
  __shared__ __align__(16) _Float16 Ah[128*LDP];
  __shared__ __align__(16) _Float16 Al[128*LDP];
  __shared__ __align__(16) _Float16 Bh[128*LDP];
  __shared__ __align__(16) _Float16 Bl[128*LDP];
  int b = blockIdx.z;
  int sp0 = blockIdx.x * 128;
  int co0 = blockIdx.y * 128;
  const float* Xb = X + ((size_t)b*NCOLS + sp0) * ldX;
  int t = threadIdx.x;
  int srow = t >> 1;
  int skoff = (t & 1) * 16;
  int wid = t >> 6, lane = t & 63;
  int wr = (wid >> 1) * 64, wc = (wid & 1) * 64;
  int lrow = lane & 15, lk = (lane >> 4) * 8;
  f32x4 acc[4][4];
#pragma unroll
  for (int f = 0; f < 4; ++f)
#pragma unroll
    for (int g = 0; g < 4; ++g)
#pragma unroll
      for (int r = 0; r < 4; ++r) acc[f][g][r] = 0.0f;

  for (int k0 = 0; k0 < Cin; k0 += 32) {
    const float* xs = Xb + (size_t)srow*ldX + k0 + skoff;
    const float* wsrc = W + (size_t)(co0 + srow)*Cin + k0 + skoff;
    float xv[16], wv[16];
    *(float4*)&xv[0]  = *(const float4*)&xs[0];
    *(float4*)&xv[4]  = *(const float4*)&xs[4];
    *(float4*)&xv[8]  = *(const float4*)&xs[8];
    *(float4*)&xv[12] = *(const float4*)&xs[12];
    *(float4*)&wv[0]  = *(const float4*)&wsrc[0];
    *(float4*)&wv[4]  = *(const float4*)&wsrc[4];
    *(float4*)&wv[8]  = *(const float4*)&wsrc[8];
    *(float4*)&wv[12] = *(const float4*)&wsrc[12];
    _Float16 xh[16], xl[16], wh[16], wl[16];
#pragma unroll
    for (int j = 0; j < 16; ++j) {
      _Float16 h = (_Float16)xv[j];
      xh[j] = h; xl[j] = (_Float16)(xv[j] - (float)h);
      _Float16 hw = (_Float16)wv[j];
      wh[j] = hw; wl[j] = (_Float16)(wv[j] - (float)hw);
    }
    *(f16x8*)&Ah[srow*LDP + skoff]     = *(f16x8*)&xh[0];
    *(f16x8*)&Ah[srow*LDP + skoff + 8] = *(f16x8*)&xh[8];
    *(f16x8*)&Al[srow*LDP + skoff]     = *(f16x8*)&xl[0];
    *(f16x8*)&Al[srow*LDP + skoff + 8] = *(f16x8*)&xl[8];
    *(f16x8*)&Bh[srow*LDP + skoff]     = *(f16x8*)&wh[0];
    *(f16x8*)&Bh[srow*LDP + skoff + 8] = *(f16x8*)&wh[8];
    *(f16x8*)&Bl[srow*LDP + skoff]     = *(f16x8*)&wl[0];
    *(f16x8*)&Bl[srow*LDP + skoff + 8] = *(f16x8*)&wl[8];
    __syncthreads();
    f16x8 ah[4], al[4], bh[4], bl[4];
#pragma unroll
    for (int f = 0; f < 4; ++f) {
      ah[f] = *(f16x8*)&Ah[(wr + f*16 + lrow)*LDP + lk];
      al[f] = *(f16x8*)&Al[(wr + f*16 + lrow)*LDP + lk];
      bh[f] = *(f16x8*)&Bh[(wc + f*16 + lrow)*LDP + lk];
      bl[f] = *(f16x8*)&Bl[(wc + f*16 + lrow)*LDP + lk];
    }
#pragma unroll
    for (int f = 0; f < 4; ++f)
#pragma unroll
      for (int g = 0; g < 4; ++g) {
        acc[f][g] = __builtin_amdgcn_mfma_f32_16x16x32_f16(ah[f], bh[g], acc[f][g], 0, 0, 0);
        acc[f][g] = __builtin_amdgcn_mfma_f32_16x16x32_f16(ah[f], bl[g], acc[f][g], 0, 0, 0);
        acc[f][g] = __builtin_amdgcn_mfma_f32_16x16x32_f16(al[f], bh[g], acc[f][g], 0, 0, 0);
      }
    __syncthreads();
  }
  int lr0 = (lane >> 4) * 4, lc = lane & 15;
#pragma unroll
  for (int f = 0; f < 4; ++f)
#pragma unroll
    for (int g = 0; g < 4; ++g)
#pragma unroll
      for (int r = 0; r < 4; ++r) {
        int sp = sp0 + wr + f*16 + lr0 + r;
        int co = co0 + wc + g*16 + lc;
        float val = acc[f][g][r];
        if (addZ) val += Z[((size_t)b*NCOLS + sp)*ldZ + co];
        Y[((size_t)b*NCOLS + sp)*ldY + co] = val;
      }
}

// ---------------------------------------------------------------------------
// vn_leaky (channel-fast): D[col][c] updated in place.
// ---------------------------------------------------------------------------
__global__ __launch_bounds__(256) void leaky_kernel(
    const float* __restrict__ X, float* __restrict__ D,
    int cmask, int cshift, int ld) {
  long id = (long)blockIdx.x*256 + threadIdx.x;
  int c = (int)(id & cmask);
  long r = id >> cshift;
  int n = (int)(r & (NPTS-1));
  int b = (int)(r >> 12);
  size_t base = ((size_t)b*NCOLS + n)*ld + c;
  size_t vs = (size_t)NPTS*ld;
  float x0 = X[base], x1 = X[base+vs], x2 = X[base+2*vs];
  float d0 = D[base], d1 = D[base+vs], d2 = D[base+2*vs];
  float dot = x0*d0 + x1*d1 + x2*d2;
  float u0 = x0, u1 = x1, u2 = x2;
  if (dot < 0.0f) {
    float dsq = d0*d0 + d1*d1 + d2*d2;
    float s = dot / (dsq + 1e-6f);
    u0 = x0 - s*d0; u1 = x1 - s*d1; u2 = x2 - s*d2;
  }
  D[base] = u0; D[base+vs] = u1; D[base+2*vs] = u2;
}

// ---------------------------------------------------------------------------
// pool over N — PER-CHANNEL argmax (matches reference: argmax per (b,c)).
// ---------------------------------------------------------------------------
__global__ __launch_bounds__(256) void pool1_kernel(
    const float* __restrict__ Net, const float* __restrict__ Dm,
    double* __restrict__ pv, int* __restrict__ pn, int ldN, int ldD) {
  __shared__ double sv[256];
  __shared__ int sn[256];
  int b = blockIdx.y;
  int n0 = blockIdx.x * 256;
  int c = threadIdx.x & 127;
  int half = threadIdx.x >> 7;
  double bv = DNEG_INF; int bn = 0x7fffffff;
  for (int i = 0; i < 128; ++i) {
    int n = n0 + 2*i + half;
    size_t r0 = ((size_t)b*NCOLS + n);
    double dot =
        (double)Net[(r0)*ldN + c]              * (double)Dm[(r0)*ldD + c]
      + (double)Net[(r0 + NPTS)*ldN + c]       * (double)Dm[(r0 + NPTS)*ldD + c]
      + (double)Net[(r0 + 2*NPTS)*ldN + c]     * (double)Dm[(r0 + 2*NPTS)*ldD + c];
    if (dot > bv) { bv = dot; bn = n; }
  }
  sv[threadIdx.x] = bv; sn[threadIdx.x] = bn;
  __syncthreads();
  if (half == 0) {
    double v1 = sv[threadIdx.x + 128]; int n1 = sn[threadIdx.x + 128];
    if (v1 > bv || (v1 == bv && n1 < bn)) { bv = v1; bn = n1; }
    pv[((size_t)b*16 + blockIdx.x)*128 + c] = bv;
    pn[((size_t)b*16 + blockIdx.x)*128 + c] = bn;
  }
}

// stage 2: per (b,c) merge 16 chunk partials (ascending n order), gather.
__global__ __launch_bounds__(128) void pool2_kernel(
    const double* __restrict__ pv, const int* __restrict__ pn,
    const float* __restrict__ Net, float* __restrict__ pooled, int ldN) {
  int b = blockIdx.x, c = threadIdx.x;
  double bv = DNEG_INF; int bn = 0x7fffffff;
  for (int ch = 0; ch < 16; ++ch) {
    double v = pv[((size_t)b*16 + ch)*128 + c];
    int nn = pn[((size_t)b*16 + ch)*128 + c];
    if (v > bv || (v == bv && nn < bn)) { bv = v; bn = nn; }
  }
#pragma unroll
  for (int v = 0; v < 3; ++v)
    pooled[(size_t)b*384 + c*3 + v] = Net[((size_t)b*NCOLS + v*NPTS + bn)*ldN + c];
}

// broadcast pooled into channels 128..255 (channel-fast)
__global__ __launch_bounds__(256) void bcast_kernel(
    const float* __restrict__ pooled, float* __restrict__ Xn) {
  int b = blockIdx.y;
  int id = blockIdx.x*256 + threadIdx.x;   // NCOLS*128
  int c = id & 127;
  int col = id >> 7;
  int v = col >> 12;
  Xn[((size_t)b*NCOLS + col)*256 + 128 + c] = pooled[(size_t)b*384 + c*3 + v];
}

// ---------------------------------------------------------------------------
// head: c = fcc_W @ vn_leaky(pooled, actc_Wd @ pooled) ; out [B,192]
// ---------------------------------------------------------------------------
__global__ __launch_bounds__(128) void head_kernel(
    const float* __restrict__ pooled, const float* __restrict__ Wa,
    const float* __restrict__ Wc, float* __restrict__ out) {
  __shared__ float xp[128*3], up[128*3];
  int b = blockIdx.x, c = threadIdx.x;
#pragma unroll
  for (int v = 0; v < 3; ++v) xp[c*3+v] = pooled[(size_t)b*384 + c*3 + v];
  __syncthreads();
  float a0 = 0.f, a1 = 0.f, a2 = 0.f;
  for (int j = 0; j < 128; ++j) {
    float w = Wa[c*128+j];
    a0 += w*xp[j*3+0]; a1 += w*xp[j*3+1]; a2 += w*xp[j*3+2];
  }
  float x0 = xp[c*3+0], x1 = xp[c*3+1], x2 = xp[c*3+2];
  float dot = x0*a0 + x1*a1 + x2*a2;
  float u0 = x0, u1 = x1, u2 = x2;
  if (dot < 0.0f) {
    float dsq = a0*a0 + a1*a1 + a2*a2;
    float s = dot / (dsq + 1e-6f);
    u0 = x0 - s*a0; u1 = x1 - s*a1; u2 = x2 - s*a2;
  }
  up[c*3+0] = u0; up[c*3+1] = u1; up[c*3+2] = u2;
  __syncthreads();
  if (c < 64) {
    float o0 = 0.f, o1 = 0.f, o2 = 0.f;
    for (int j = 0; j < 128; ++j) {
      float w = Wc[c*128+j];
      o0 += w*up[j*3+0]; o1 += w*up[j*3+1]; o2 += w*up[j*3+2];
    }
    out[(size_t)b*192 + c*3 + 0] = o0;
    out[(size_t)b*192 + c*3 + 1] = o1;
    out[(size_t)b*192 + c*3 + 2] = o2;
  }
}

// ---------------------------------------------------------------------------
extern "C" void kernel_launch(void* const* d_in, const int* in_sizes, int n_in,
                              void* d_out, int out_size, void* d_ws, size_t ws_size,
                              hipStream_t stream) {
  const float* pc    = (const float*)d_in[0];
  const float* cWf   = (const float*)d_in[1];
  const float* cWd   = (const float*)d_in[2];
  const float* pposW = (const float*)d_in[3];
  const float* fcW   = (const float*)d_in[4];
  const float* ba0   = (const float*)d_in[5];
  const float* bf0   = (const float*)d_in[6];
  const float* ba1   = (const float*)d_in[7];
  const float* bf1   = (const float*)d_in[8];
  const float* bscW  = (const float*)d_in[9];
  const float* pWd   = (const float*)d_in[10];
  const float* aWd   = (const float*)d_in[11];
  const float* fccW  = (const float*)d_in[12];
  float* out = (float*)d_out;
  char* ws = (char*)d_ws;
  const size_t MB = 1u << 20;
  const size_t KB = 1u << 10;
  // workspace (channel-fast activations [b][col][c]):
  int*    idxb   = (int*)(ws);                 // 1.25 MB
  float*  X1     = (float*)(ws + 2*MB);        // 48 MB  [B][NCOLS][256]
  float*  X2     = (float*)(ws + 52*MB);       // 48 MB
  float*  conv   = (float*)(ws + 52*MB);       // 12 MB [B][NCOLS][64] (aliases X2)
  float*  T      = (float*)(ws + 102*MB);      // 48 MB [B][NCOLS][256]
  float*  T2     = T;                          // 24 MB [B][NCOLS][128] (aliases T)
  float*  DX     = (float*)(ws + 126*MB);      // 24 MB [B][NCOLS][128]
  float*  Hn     = (float*)(ws + 152*MB);      // 24 MB [B][NCOLS][128]
  float*  pooled = (float*)(ws + 178*MB);      // [B][384]
  double* pv     = (double*)(ws + 178*MB + 64*KB);   // 64 KB [B][16][128]
  int*    pn     = (int*)(ws + 178*MB + 128*KB);     // 32 KB

  knn_kernel<<<NB*NPTS/4, 256, 0, stream>>>(pc, idxb);
  edgeconv_kernel<<<NB*NPTS/2, 128, 0, stream>>>(pc, idxb, cWf, cWd, pposW, conv);
  gemm_mfma<<<dim3(96, 2, NB), 256, 0, stream>>>(fcW, conv, nullptr, X1,
      64, 64, 256, 0, 0);

  float* Xin = X1; float* Xout = X2;
  for (int i = 0; i < 5; ++i) {
    const float* a0 = ba0 + (size_t)i*256*256;
    const float* f0 = bf0 + (size_t)i*128*256;
    const float* a1 = ba1 + (size_t)i*128*128;
    const float* f1 = bf1 + (size_t)i*128*128;
    const float* sc = bscW + (size_t)i*128*256;
    const float* pw = pWd + (size_t)i*128*128;
    // T = a0 @ X ; U = leaky(X, T) in place
    gemm_mfma<<<dim3(96,2,NB),256,0,stream>>>(a0, Xin, nullptr, T, 256, 256, 256, 0, 0);
    leaky_kernel<<<NB*NPTS*256/256,256,0,stream>>>(Xin, T, 255, 8, 256);
    // Hn = f0 @ U
    gemm_mfma<<<dim3(96,1,NB),256,0,stream>>>(f0, T, nullptr, Hn, 256, 256, 128, 0, 0);
    // T2 = a1 @ Hn ; U2 = leaky(Hn, T2)
    gemm_mfma<<<dim3(96,1,NB),256,0,stream>>>(a1, Hn, nullptr, T2, 128, 128, 128, 0, 0);
    leaky_kernel<<<NB*NPTS*128/256,256,0,stream>>>(Hn, T2, 127, 7, 128);
    // DX = f1 @ U2
    gemm_mfma<<<dim3(96,1,NB),256,0,stream>>>(f1, T2, nullptr, DX, 128, 128, 128, 0, 0);
    // Xout[ch 0..127] = sc @ Xin + DX
    gemm_mfma<<<dim3(96,1,NB),256,0,stream>>>(sc, Xin, DX, Xout, 256, 256, 256, 128, 1);
    // Dm = pw @ net -> Hn
    gemm_mfma<<<dim3(96,1,NB),256,0,stream>>>(pw, Xout, nullptr, Hn, 128, 256, 128, 0, 0);
    pool1_kernel<<<dim3(16,NB),256,0,stream>>>(Xout, Hn, pv, pn, 256, 128);
    pool2_kernel<<<NB,128,0,stream>>>(pv, pn, Xout, pooled, 256);
    if (i < 4) {
      bcast_kernel<<<dim3(NCOLS*128/256,NB),256,0,stream>>>(pooled, Xout);
      float* tmp = Xin; Xin = Xout; Xout = tmp;
    }
  }
  head_kernel<<<NB,128,0,stream>>>(pooled, aWd, fccW, out);
}